// Round 3
// baseline (395.430 us; speedup 1.0000x reference)
//
#include <hip/hip_runtime.h>

typedef short short8 __attribute__((ext_vector_type(8)));
typedef float f32x4 __attribute__((ext_vector_type(4)));

__device__ __forceinline__ float bf2f(unsigned short u) {
  union { unsigned int i; float f; } v; v.i = ((unsigned int)u) << 16; return v.f;
}
__device__ __forceinline__ unsigned short f2bf(float f) {
  unsigned int x = __float_as_uint(f);
  unsigned int r = (x + 0x7fffu + ((x >> 16) & 1u)) >> 16;  // RNE
  return (unsigned short)r;
}

typedef __attribute__((address_space(1))) void* gas_t;
typedef __attribute__((address_space(3))) void* las_t;
__device__ __forceinline__ void async16(const float* g, float* l) {
  __builtin_amdgcn_global_load_lds((gas_t)g, (las_t)l, 16, 0, 0);
}

// Counted vmem wait (T4); sched_barrier(0) per guide rule #18.
template <int N>
__device__ __forceinline__ void wait_vm() {
  asm volatile("s_waitcnt vmcnt(%0)" :: "n"(N) : "memory");
  __builtin_amdgcn_sched_barrier(0);
}

// lgkm-only barrier: does NOT drain vmcnt, so ring-prefetch global_load_lds
// ops stay in flight across phase-A synchronization (raw s_barrier has no
// implicit waitcnt, unlike __syncthreads which emits vmcnt(0)).
__device__ __forceinline__ void barrier_lgkm() {
  asm volatile("s_waitcnt lgkmcnt(0)" ::: "memory");
  __builtin_amdgcn_sched_barrier(0);
  __builtin_amdgcn_s_barrier();
}

// ---------------------------------------------------------------------------
// K0: build combined matrices in MFMA B-fragment layout (bf16).
//   A[k=p][n=g*64+d]    = 0.25 * sum_c Wq[p][16g+c] * Wk[d][16g+c]
//   WVO[k=g*64+d][n=q'] =        sum_c Wv[d][16g+c] * Wout[16g+c][q']
// frag layout: elem(k,n) -> (k>>5)*8192 + n*32 + (k&31)
// ---------------------------------------------------------------------------
__global__ __launch_bounds__(256) void prep_kernel(
    const float* __restrict__ Wq, const float* __restrict__ Wk,
    const float* __restrict__ Wv, const float* __restrict__ Wout,
    unsigned short* __restrict__ Afrag, unsigned short* __restrict__ WVOfrag) {
  const int b = blockIdx.x, tid = threadIdx.x;
  if (b < 256) {
    const int p = b, g = tid >> 6, d = tid & 63;
    float s = 0.f;
#pragma unroll
    for (int c = 0; c < 16; ++c)
      s += Wq[p * 64 + g * 16 + c] * Wk[d * 64 + g * 16 + c];
    s *= 0.25f;  // 1/sqrt(PPG) folded into scores
    const int n = g * 64 + d, k = p;
    Afrag[(size_t)(k >> 5) * 8192 + n * 32 + (k & 31)] = f2bf(s);
  } else {
    const int row = b - 256, g = row >> 6, d = row & 63, q = tid;
    float s = 0.f;
#pragma unroll
    for (int c = 0; c < 16; ++c)
      s += Wv[d * 64 + g * 16 + c] * Wout[(g * 16 + c) * 256 + q];
    WVOfrag[(size_t)(row >> 5) * 8192 + q * 32 + (row & 31)] = f2bf(s);
  }
}

// ---------------------------------------------------------------------------
// K1: fused, 32 pixel-rows per WG, 2 WGs/CU (73 KB LDS).
// vmcnt-FIFO-aware issue order: q loads (oldest) -> Afrag B-frags (hoisted to
// registers) -> ring asyncs (youngest). Phase-A waits are then counted
// (vmcnt(12)) and the 6-tile ring fill overlaps phase A's MFMAs. Phase-A
// barriers are lgkm-only (no vmcnt drain). Phase B barrier-free, depth-7
// ring, counted vmcnt(10). qA/qk/y share one LDS buffer.
// ---------------------------------------------------------------------------
__global__ __launch_bounds__(256, 2) void fused_kernel(
    const float* __restrict__ q, const float* __restrict__ kv,
    const unsigned short* __restrict__ Afrag,
    const unsigned short* __restrict__ WVOfrag,
    const float* __restrict__ bias, float* __restrict__ Out) {
  __shared__ float kvbuf[7][2048];           // 56 KB ring (7 x 32rows x 64ch)
  __shared__ unsigned short qbuf[32 * 264];  // 16.9 KB: qA stage, qk, then y

  const int tid = threadIdx.x;
  const int wgid = blockIdx.x;  // ((n*64+i)<<1) | half
  const int w = tid >> 6, lane = tid & 63;
  const int m_l = lane & 15, quad = lane >> 4;

  // kv base for this WG's 32 rows: (n<<24) + (i<<12) + half*32*64
  const float* kvbase = kv + ((size_t)(wgid >> 7) << 24) +
                        ((size_t)((wgid >> 1) & 63) << 12) +
                        ((size_t)(wgid & 1) << 11);
  const int loff = w * 512 + lane * 4;  // wave-private ring quarter (floats)

  // ---- 1) q loads (oldest in vmcnt FIFO) ---------------------------------
  const float* qrow = q + (size_t)(wgid >> 1) * 16384 + (size_t)(wgid & 1) * 8192;
  const int r = tid >> 3, cc = (tid & 7) * 32;
  const float4* xp = (const float4*)(qrow + r * 256 + cc);
  float4 xv[8];
#pragma unroll
  for (int kk = 0; kk < 8; ++kk) xv[kk] = xp[kk];
  __builtin_amdgcn_sched_barrier(0);

  // ---- 2) Afrag B-fragments for this wave, hoisted to registers ----------
  short8 bfr[8][4];
#pragma unroll
  for (int ks = 0; ks < 8; ++ks)
#pragma unroll
    for (int ntl = 0; ntl < 4; ++ntl)
      bfr[ks][ntl] = *(const short8*)(Afrag +
          ((size_t)ks * 256 + (w * 4 + ntl) * 16 + m_l) * 32 + quad * 8);
  __builtin_amdgcn_sched_barrier(0);

  // ---- 3) ring prefetch tiles 0..5 (youngest; outstanding through A) -----
#pragma unroll
  for (int tt = 0; tt < 6; ++tt) {
    const float* src = kvbase + ((size_t)tt << 18) + loff;
    float* dst = &kvbuf[tt][loff];
    async16(src, dst);
    async16(src + 256, dst + 256);
  }
  __builtin_amdgcn_sched_barrier(0);

  // ---------------- Phase A: qk(32x256) = q_rows @ A ----------------------
#pragma unroll
  for (int kk = 0; kk < 4; ++kk) {
    float4 x0 = xv[2 * kk], x1 = xv[2 * kk + 1];
    short8 vv;
    vv[0] = (short)f2bf(x0.x); vv[1] = (short)f2bf(x0.y);
    vv[2] = (short)f2bf(x0.z); vv[3] = (short)f2bf(x0.w);
    vv[4] = (short)f2bf(x1.x); vv[5] = (short)f2bf(x1.y);
    vv[6] = (short)f2bf(x1.z); vv[7] = (short)f2bf(x1.w);
    *(short8*)&qbuf[r * 264 + cc + kk * 8] = vv;
  }
  barrier_lgkm();
  {
    // Column-split: wave w computes nt in [w*4, w*4+4), both 16-row m-tiles.
    f32x4 acc[2][4];
#pragma unroll
    for (int mt = 0; mt < 2; ++mt)
#pragma unroll
      for (int ntl = 0; ntl < 4; ++ntl) acc[mt][ntl] = (f32x4){0.f, 0.f, 0.f, 0.f};
#pragma unroll
    for (int ks = 0; ks < 8; ++ks) {
      short8 a0 = *(const short8*)&qbuf[m_l * 264 + ks * 32 + quad * 8];
      short8 a1 = *(const short8*)&qbuf[(16 + m_l) * 264 + ks * 32 + quad * 8];
#pragma unroll
      for (int ntl = 0; ntl < 4; ++ntl) {
        acc[0][ntl] = __builtin_amdgcn_mfma_f32_16x16x32_bf16(a0, bfr[ks][ntl], acc[0][ntl], 0, 0, 0);
        acc[1][ntl] = __builtin_amdgcn_mfma_f32_16x16x32_bf16(a1, bfr[ks][ntl], acc[1][ntl], 0, 0, 0);
      }
    }
    barrier_lgkm();  // all waves done reading qA before overwrite
    // C/D: col=lane&15, row=quad*4+r -> qk into the same buffer
#pragma unroll
    for (int mt = 0; mt < 2; ++mt)
#pragma unroll
      for (int ntl = 0; ntl < 4; ++ntl) {
        const int col = (w * 4 + ntl) * 16 + m_l;
#pragma unroll
        for (int r4 = 0; r4 < 4; ++r4)
          qbuf[(mt * 16 + quad * 4 + r4) * 264 + col] = f2bf(acc[mt][ntl][r4]);
      }
  }
  barrier_lgkm();  // qk visible to all waves; ring asyncs still in flight

  // ---------------- Phase B: streaming attention (barrier-free) -----------
  // Thread = (row jl, group g, channel-half h): 32 channels each.
  const int jl = tid >> 3, sub = tid & 7, g = sub >> 1, h = sub & 1;

  float qf[32];
#pragma unroll
  for (int c = 0; c < 8; ++c) {
    const int rot = (c + jl) & 7;
    uint2 u = *(const uint2*)&qbuf[jl * 264 + g * 64 + h * 32 + rot * 4];
    qf[4 * c + 0] = bf2f((unsigned short)(u.x & 0xffffu));
    qf[4 * c + 1] = bf2f((unsigned short)(u.x >> 16));
    qf[4 * c + 2] = bf2f((unsigned short)(u.y & 0xffffu));
    qf[4 * c + 3] = bf2f((unsigned short)(u.y >> 16));
  }

  float yac[32];
#pragma unroll
  for (int c = 0; c < 32; ++c) yac[c] = 0.f;
  float lsum = 0.f;

  auto stepT = [&](int slot) {
    const float* row = &kvbuf[slot][jl * 64 + h * 32];
    float s = 0.f;
    float4 cv[8];
#pragma unroll
    for (int c = 0; c < 8; ++c) {
      const int rot = (c + jl) & 7;
      cv[c] = *(const float4*)(row + rot * 4);
      s = fmaf(cv[c].x, qf[4 * c + 0], s);
      s = fmaf(cv[c].y, qf[4 * c + 1], s);
      s = fmaf(cv[c].z, qf[4 * c + 2], s);
      s = fmaf(cv[c].w, qf[4 * c + 3], s);
    }
    const float so = __shfl_xor(s, 1, 64);  // combine channel halves
    const float p = __expf(s + so);
    lsum += p;
#pragma unroll
    for (int c = 0; c < 8; ++c) {
      yac[4 * c + 0] = fmaf(p, cv[c].x, yac[4 * c + 0]);
      yac[4 * c + 1] = fmaf(p, cv[c].y, yac[4 * c + 1]);
      yac[4 * c + 2] = fmaf(p, cv[c].z, yac[4 * c + 2]);
      yac[4 * c + 3] = fmaf(p, cv[c].w, yac[4 * c + 3]);
    }
  };

  // Main loop: wait tile t home (<=10 outstanding = t+1..t+5 in flight),
  // issue t+6, compute t. 2 loads/tile/wave; never drain in-loop.
  int sb = 0, si = 6;
#pragma unroll 1
  for (int t = 0; t < 58; ++t) {
    wait_vm<10>();
    const float* src = kvbase + ((size_t)(t + 6) << 18) + loff;
    float* dst = &kvbuf[si][loff];
    async16(src, dst);
    async16(src + 256, dst + 256);
    stepT(sb);
    sb = (sb == 6) ? 0 : sb + 1;
    si = (si == 6) ? 0 : si + 1;
  }
  // Tail t=58..63 (slots 2,3,4,5,6,0), exact decreasing counts.
  wait_vm<10>(); stepT(2);
  wait_vm<8>();  stepT(3);
  wait_vm<6>();  stepT(4);
  wait_vm<4>();  stepT(5);
  wait_vm<2>();  stepT(6);
  wait_vm<0>();  stepT(0);

  // y -> qbuf (bf16), mirror of qf addressing (wave-private rows)
  {
    const float inv = 1.f / lsum;
#pragma unroll
    for (int c = 0; c < 8; ++c) {
      const int rot = (c + jl) & 7;
      uint2 pk;
      pk.x = (unsigned int)f2bf(yac[4 * c + 0] * inv) |
             ((unsigned int)f2bf(yac[4 * c + 1] * inv) << 16);
      pk.y = (unsigned int)f2bf(yac[4 * c + 2] * inv) |
             ((unsigned int)f2bf(yac[4 * c + 3] * inv) << 16);
      *(uint2*)&qbuf[jl * 264 + g * 64 + h * 32 + rot * 4] = pk;
    }
  }
  barrier_lgkm();

  // ---------------- Phase C: out(32x256) = y @ WVO + bias -----------------
  {
    f32x4 acc[2][4];
#pragma unroll
    for (int mt = 0; mt < 2; ++mt)
#pragma unroll
      for (int ntl = 0; ntl < 4; ++ntl) acc[mt][ntl] = (f32x4){0.f, 0.f, 0.f, 0.f};
#pragma unroll
    for (int ks = 0; ks < 8; ++ks) {
      short8 a0 = *(const short8*)&qbuf[m_l * 264 + ks * 32 + quad * 8];
      short8 a1 = *(const short8*)&qbuf[(16 + m_l) * 264 + ks * 32 + quad * 8];
#pragma unroll
      for (int ntl = 0; ntl < 4; ++ntl) {
        short8 bf = *(const short8*)(WVOfrag +
            ((size_t)ks * 256 + (w * 4 + ntl) * 16 + m_l) * 32 + quad * 8);
        acc[0][ntl] = __builtin_amdgcn_mfma_f32_16x16x32_bf16(a0, bf, acc[0][ntl], 0, 0, 0);
        acc[1][ntl] = __builtin_amdgcn_mfma_f32_16x16x32_bf16(a1, bf, acc[1][ntl], 0, 0, 0);
      }
    }
    float* outb = Out + (size_t)(wgid >> 1) * 16384 + (size_t)(wgid & 1) * 8192;
#pragma unroll
    for (int mt = 0; mt < 2; ++mt)
#pragma unroll
      for (int ntl = 0; ntl < 4; ++ntl) {
        const int col = (w * 4 + ntl) * 16 + m_l;
        const float bb = bias[col];
#pragma unroll
        for (int r4 = 0; r4 < 4; ++r4)
          outb[(size_t)(mt * 16 + quad * 4 + r4) * 256 + col] = acc[mt][ntl][r4] + bb;
      }
  }
}

// ---------------------------------------------------------------------------
extern "C" void kernel_launch(void* const* d_in, const int* in_sizes, int n_in,
                              void* d_out, int out_size, void* d_ws,
                              size_t ws_size, hipStream_t stream) {
  const float* q    = (const float*)d_in[0];
  const float* kv   = (const float*)d_in[1];
  const float* Wq   = (const float*)d_in[2];
  const float* Wk   = (const float*)d_in[3];
  const float* Wv   = (const float*)d_in[4];
  const float* Wout = (const float*)d_in[5];
  const float* bout = (const float*)d_in[6];

  unsigned short* ws      = (unsigned short*)d_ws;
  unsigned short* Afrag   = ws;            // 65536 shorts
  unsigned short* WVOfrag = ws + 65536;    // 65536 shorts

  hipLaunchKernelGGL(prep_kernel, dim3(512), dim3(256), 0, stream,
                     Wq, Wk, Wv, Wout, Afrag, WVOfrag);
  hipLaunchKernelGGL(fused_kernel, dim3(512), dim3(256), 0, stream,
                     q, kv, Afrag, WVOfrag, bout, (float*)d_out);
}

// Round 4
// 383.925 us; speedup vs baseline: 1.0300x; 1.0300x over previous
//
#include <hip/hip_runtime.h>

typedef short short8 __attribute__((ext_vector_type(8)));
typedef float f32x4 __attribute__((ext_vector_type(4)));

__device__ __forceinline__ float bf2f(unsigned short u) {
  union { unsigned int i; float f; } v; v.i = ((unsigned int)u) << 16; return v.f;
}
__device__ __forceinline__ unsigned short f2bf(float f) {
  unsigned int x = __float_as_uint(f);
  unsigned int r = (x + 0x7fffu + ((x >> 16) & 1u)) >> 16;  // RNE
  return (unsigned short)r;
}

typedef __attribute__((address_space(1))) void* gas_t;
typedef __attribute__((address_space(3))) void* las_t;
__device__ __forceinline__ void async16(const float* g, float* l) {
  __builtin_amdgcn_global_load_lds((gas_t)g, (las_t)l, 16, 0, 0);
}

// Counted vmem wait (T4); sched_barrier(0) per guide rule #18.
template <int N>
__device__ __forceinline__ void wait_vm() {
  asm volatile("s_waitcnt vmcnt(%0)" :: "n"(N) : "memory");
  __builtin_amdgcn_sched_barrier(0);
}

// ---------------------------------------------------------------------------
// K0: build combined matrices in MFMA B-fragment layout (bf16).
//   A[k=p][n=g*64+d]    = 0.25 * sum_c Wq[p][16g+c] * Wk[d][16g+c]
//   WVO[k=g*64+d][n=q'] =        sum_c Wv[d][16g+c] * Wout[16g+c][q']
// frag layout: elem(k,n) -> (k>>5)*8192 + n*32 + (k&31)
// ---------------------------------------------------------------------------
__global__ __launch_bounds__(256) void prep_kernel(
    const float* __restrict__ Wq, const float* __restrict__ Wk,
    const float* __restrict__ Wv, const float* __restrict__ Wout,
    unsigned short* __restrict__ Afrag, unsigned short* __restrict__ WVOfrag) {
  const int b = blockIdx.x, tid = threadIdx.x;
  if (b < 256) {
    const int p = b, g = tid >> 6, d = tid & 63;
    float s = 0.f;
#pragma unroll
    for (int c = 0; c < 16; ++c)
      s += Wq[p * 64 + g * 16 + c] * Wk[d * 64 + g * 16 + c];
    s *= 0.25f;  // 1/sqrt(PPG) folded into scores
    const int n = g * 64 + d, k = p;
    Afrag[(size_t)(k >> 5) * 8192 + n * 32 + (k & 31)] = f2bf(s);
  } else {
    const int row = b - 256, g = row >> 6, d = row & 63, q = tid;
    float s = 0.f;
#pragma unroll
    for (int c = 0; c < 16; ++c)
      s += Wv[d * 64 + g * 16 + c] * Wout[(g * 16 + c) * 256 + q];
    WVOfrag[(size_t)(row >> 5) * 8192 + q * 32 + (row & 31)] = f2bf(s);
  }
}

// ---------------------------------------------------------------------------
// K1: fused, HALF-ROW granularity. One WG per (n,i,half): 32 pixel-rows.
// LDS 73 KB -> 2 WGs/CU (2 waves/SIMD): co-resident WG provides TLP so the
// memory pipe never drains during the serial matrix phases. Ring prefetch
// issued at kernel top so it fills under phase A. Phase B barrier-free,
// counted vmcnt. (Round-3 variant — reg-hoisted Afrag + lgkm-only barriers —
// measured −4.7 µs: hoist cost ~200 live VGPRs; the barrier vmcnt drain is
// mandatory HBM stream time either way. Kept the simpler round-2 form.)
// ---------------------------------------------------------------------------
__global__ __launch_bounds__(256, 2) void fused_kernel(
    const float* __restrict__ q, const float* __restrict__ kv,
    const unsigned short* __restrict__ Afrag,
    const unsigned short* __restrict__ WVOfrag,
    const float* __restrict__ bias, float* __restrict__ Out) {
  __shared__ float kvbuf[5][2048];           // 40 KB ring (5 x 32rows x 64ch)
  __shared__ unsigned short qk_s[32 * 264];  // 16.9 KB qk, reused for y
  __shared__ unsigned short qA_s[32 * 264];  // 16.9 KB bf16 q staging

  const int tid = threadIdx.x;
  const int wgid = blockIdx.x;  // ((n*64+i)<<1) | half
  const int w = tid >> 6, lane = tid & 63;
  const int m_l = lane & 15, quad = lane >> 4;

  // kv base for this WG's 32 rows: (n<<24) + (i<<12) + half*32*64
  const float* kvbase = kv + ((size_t)(wgid >> 7) << 24) +
                        ((size_t)((wgid >> 1) & 63) << 12) +
                        ((size_t)(wgid & 1) << 11);
  const int loff = w * 512 + lane * 4;  // wave-private ring quarter (floats)

  // ---- Ring prefetch tiles 0..3 FIRST: DMA fills under phase A -----------
#pragma unroll
  for (int tt = 0; tt < 4; ++tt) {
    const float* src = kvbase + ((size_t)tt << 18) + loff;
    float* dst = &kvbuf[tt][loff];
    async16(src, dst);
    async16(src + 256, dst + 256);
  }

  // ---------------- Phase A: qk(32x256) = q_rows @ A ----------------------
  {
    const float* qrow = q + (size_t)(wgid >> 1) * 16384 + (size_t)(wgid & 1) * 8192;
    const int r = tid >> 3, cc = (tid & 7) * 32;
    const float4* xp = (const float4*)(qrow + r * 256 + cc);
#pragma unroll
    for (int kk = 0; kk < 4; ++kk) {
      float4 x0 = xp[2 * kk], x1 = xp[2 * kk + 1];
      short8 vv;
      vv[0] = (short)f2bf(x0.x); vv[1] = (short)f2bf(x0.y);
      vv[2] = (short)f2bf(x0.z); vv[3] = (short)f2bf(x0.w);
      vv[4] = (short)f2bf(x1.x); vv[5] = (short)f2bf(x1.y);
      vv[6] = (short)f2bf(x1.z); vv[7] = (short)f2bf(x1.w);
      *(short8*)&qA_s[r * 264 + cc + kk * 8] = vv;
    }
  }
  __syncthreads();
  {
    // Column-split: wave w computes nt in [w*4, w*4+4), both 16-row m-tiles.
    f32x4 acc[2][4];
#pragma unroll
    for (int mt = 0; mt < 2; ++mt)
#pragma unroll
      for (int ntl = 0; ntl < 4; ++ntl) acc[mt][ntl] = (f32x4){0.f, 0.f, 0.f, 0.f};
#pragma unroll
    for (int ks = 0; ks < 8; ++ks) {
      short8 a0 = *(const short8*)&qA_s[m_l * 264 + ks * 32 + quad * 8];
      short8 a1 = *(const short8*)&qA_s[(16 + m_l) * 264 + ks * 32 + quad * 8];
#pragma unroll
      for (int ntl = 0; ntl < 4; ++ntl) {
        short8 bf = *(const short8*)(Afrag +
            ((size_t)ks * 256 + (w * 4 + ntl) * 16 + m_l) * 32 + quad * 8);
        acc[0][ntl] = __builtin_amdgcn_mfma_f32_16x16x32_bf16(a0, bf, acc[0][ntl], 0, 0, 0);
        acc[1][ntl] = __builtin_amdgcn_mfma_f32_16x16x32_bf16(a1, bf, acc[1][ntl], 0, 0, 0);
      }
    }
    // C/D: col=lane&15, row=quad*4+r
#pragma unroll
    for (int mt = 0; mt < 2; ++mt)
#pragma unroll
      for (int ntl = 0; ntl < 4; ++ntl) {
        const int col = (w * 4 + ntl) * 16 + m_l;
#pragma unroll
        for (int r4 = 0; r4 < 4; ++r4)
          qk_s[(mt * 16 + quad * 4 + r4) * 264 + col] = f2bf(acc[mt][ntl][r4]);
      }
  }
  __syncthreads();

  // ---------------- Phase B: streaming attention (barrier-free) -----------
  // Thread = (row jl, group g, channel-half h): 32 channels each.
  const int jl = tid >> 3, sub = tid & 7, g = sub >> 1, h = sub & 1;

  float qf[32];
#pragma unroll
  for (int c = 0; c < 8; ++c) {
    const int rot = (c + jl) & 7;
    uint2 u = *(const uint2*)&qk_s[jl * 264 + g * 64 + h * 32 + rot * 4];
    qf[4 * c + 0] = bf2f((unsigned short)(u.x & 0xffffu));
    qf[4 * c + 1] = bf2f((unsigned short)(u.x >> 16));
    qf[4 * c + 2] = bf2f((unsigned short)(u.y & 0xffffu));
    qf[4 * c + 3] = bf2f((unsigned short)(u.y >> 16));
  }

  float yac[32];
#pragma unroll
  for (int c = 0; c < 32; ++c) yac[c] = 0.f;
  float lsum = 0.f;

  auto stepT = [&](int slot) {
    const float* row = &kvbuf[slot][jl * 64 + h * 32];
    float s = 0.f;
    float4 cv[8];
#pragma unroll
    for (int c = 0; c < 8; ++c) {
      const int rot = (c + jl) & 7;
      cv[c] = *(const float4*)(row + rot * 4);
      s = fmaf(cv[c].x, qf[4 * c + 0], s);
      s = fmaf(cv[c].y, qf[4 * c + 1], s);
      s = fmaf(cv[c].z, qf[4 * c + 2], s);
      s = fmaf(cv[c].w, qf[4 * c + 3], s);
    }
    const float so = __shfl_xor(s, 1, 64);  // combine channel halves
    const float p = __expf(s + so);
    lsum += p;
#pragma unroll
    for (int c = 0; c < 8; ++c) {
      yac[4 * c + 0] = fmaf(p, cv[c].x, yac[4 * c + 0]);
      yac[4 * c + 1] = fmaf(p, cv[c].y, yac[4 * c + 1]);
      yac[4 * c + 2] = fmaf(p, cv[c].z, yac[4 * c + 2]);
      yac[4 * c + 3] = fmaf(p, cv[c].w, yac[4 * c + 3]);
    }
  };

  // Main loop: wait tile t home (<=6 outstanding = t+1..t+3 in flight),
  // issue t+4, compute t. 2 loads/tile/wave; never drain in-loop.
  int sb = 0, si = 4;
#pragma unroll 1
  for (int t = 0; t < 60; ++t) {
    wait_vm<6>();
    const float* src = kvbase + ((size_t)(t + 4) << 18) + loff;
    float* dst = &kvbuf[si][loff];
    async16(src, dst);
    async16(src + 256, dst + 256);
    stepT(sb);
    sb = (sb == 4) ? 0 : sb + 1;
    si = (si == 4) ? 0 : si + 1;
  }
  // Tail t=60..63 (slots 0,1,2,3), exact decreasing counts.
  wait_vm<6>(); stepT(0);
  wait_vm<4>(); stepT(1);
  wait_vm<2>(); stepT(2);
  wait_vm<0>(); stepT(3);

  // y -> qk_s (bf16), mirror of qf addressing
  {
    const float inv = 1.f / lsum;
#pragma unroll
    for (int c = 0; c < 8; ++c) {
      const int rot = (c + jl) & 7;
      uint2 pk;
      pk.x = (unsigned int)f2bf(yac[4 * c + 0] * inv) |
             ((unsigned int)f2bf(yac[4 * c + 1] * inv) << 16);
      pk.y = (unsigned int)f2bf(yac[4 * c + 2] * inv) |
             ((unsigned int)f2bf(yac[4 * c + 3] * inv) << 16);
      *(uint2*)&qk_s[jl * 264 + g * 64 + h * 32 + rot * 4] = pk;
    }
  }
  __syncthreads();

  // ---------------- Phase C: out(32x256) = y @ WVO + bias -----------------
  {
    f32x4 acc[2][4];
#pragma unroll
    for (int mt = 0; mt < 2; ++mt)
#pragma unroll
      for (int ntl = 0; ntl < 4; ++ntl) acc[mt][ntl] = (f32x4){0.f, 0.f, 0.f, 0.f};
#pragma unroll
    for (int ks = 0; ks < 8; ++ks) {
      short8 a0 = *(const short8*)&qk_s[m_l * 264 + ks * 32 + quad * 8];
      short8 a1 = *(const short8*)&qk_s[(16 + m_l) * 264 + ks * 32 + quad * 8];
#pragma unroll
      for (int ntl = 0; ntl < 4; ++ntl) {
        short8 bf = *(const short8*)(WVOfrag +
            ((size_t)ks * 256 + (w * 4 + ntl) * 16 + m_l) * 32 + quad * 8);
        acc[0][ntl] = __builtin_amdgcn_mfma_f32_16x16x32_bf16(a0, bf, acc[0][ntl], 0, 0, 0);
        acc[1][ntl] = __builtin_amdgcn_mfma_f32_16x16x32_bf16(a1, bf, acc[1][ntl], 0, 0, 0);
      }
    }
    float* outb = Out + (size_t)(wgid >> 1) * 16384 + (size_t)(wgid & 1) * 8192;
#pragma unroll
    for (int mt = 0; mt < 2; ++mt)
#pragma unroll
      for (int ntl = 0; ntl < 4; ++ntl) {
        const int col = (w * 4 + ntl) * 16 + m_l;
        const float bb = bias[col];
#pragma unroll
        for (int r4 = 0; r4 < 4; ++r4)
          outb[(size_t)(mt * 16 + quad * 4 + r4) * 256 + col] = acc[mt][ntl][r4] + bb;
      }
  }
}

// ---------------------------------------------------------------------------
extern "C" void kernel_launch(void* const* d_in, const int* in_sizes, int n_in,
                              void* d_out, int out_size, void* d_ws,
                              size_t ws_size, hipStream_t stream) {
  const float* q    = (const float*)d_in[0];
  const float* kv   = (const float*)d_in[1];
  const float* Wq   = (const float*)d_in[2];
  const float* Wk   = (const float*)d_in[3];
  const float* Wv   = (const float*)d_in[4];
  const float* Wout = (const float*)d_in[5];
  const float* bout = (const float*)d_in[6];

  unsigned short* ws      = (unsigned short*)d_ws;
  unsigned short* Afrag   = ws;            // 65536 shorts
  unsigned short* WVOfrag = ws + 65536;    // 65536 shorts

  hipLaunchKernelGGL(prep_kernel, dim3(512), dim3(256), 0, stream,
                     Wq, Wk, Wv, Wout, Afrag, WVOfrag);
  hipLaunchKernelGGL(fused_kernel, dim3(512), dim3(256), 0, stream,
                     q, kv, Afrag, WVOfrag, bout, (float*)d_out);
}